// Round 6
// baseline (270.151 us; speedup 1.0000x reference)
//
#include <hip/hip_runtime.h>

// (B,C,L,H,W) = (4,64,16,32,32), K=1024, D=C=64
constexpr int Cc   = 64;
constexpr int Kc   = 1024;
constexpr int Dc   = 64;
constexpr int LHWc = 16 * 32 * 32;        // 16384
constexpr int Nc   = 4 * LHWc;            // 65536 vectors
constexpr int QSIZE    = 4 * Cc * LHWc;   // 4194304
constexpr int OFF_LOSS = QSIZE;           // 4194304
constexpr int OFF_IDX  = QSIZE + 1;       // 4194305

constexpr int WAVES  = 4;                 // waves per block (256 threads)
constexpr int CHUNK  = 128;               // codes staged per LDS chunk (32 KB)
constexpr int NCHUNK = Kc / CHUNK;        // 8
constexpr int CPW    = CHUNK / WAVES;     // 32 codes per wave per chunk

__global__ void vq_zero(float* __restrict__ out) {
    out[OFF_LOSS] = 0.0f;
}

// Codebook now flows global -> LDS (cooperative, coalesced) -> wave-uniform
// broadcast ds_read_b128. This takes the K$/SMEM pipe (the round 3-5
// bottleneck: every s_load was a cold scalar-cache miss, ~28 cyc/miss/CU
// serialized = the observed ~200 us) out of the hot loop entirely.
__global__ __launch_bounds__(WAVES * 64)
__attribute__((amdgpu_waves_per_eu(4, 4)))
void vq_main(
    const float* __restrict__ in, const float* __restrict__ codebook,
    float* __restrict__ out)
{
    __shared__ float4 cchunk[CHUNK * 16];        // 32 KB: [code][d/4] row-major
    __shared__ float  c2s[Kc];                   // 4 KB: ||c_k||^2
    __shared__ unsigned long long red[WAVES * 64];

    const int tid  = threadIdx.x;
    const int lane = tid & 63;
    const int wave = __builtin_amdgcn_readfirstlane(tid >> 6);

    // c2 fill: 256 threads x 4 codes, exact fma chain (validated r2-r5)
#pragma unroll
    for (int j = 0; j < 4; ++j) {
        const int k = tid * 4 + j;
        const float* c = codebook + (size_t)k * Dc;
        float s = 0.f;
#pragma unroll
        for (int d = 0; d < Dc; ++d) s = __builtin_fmaf(c[d], c[d], s);
        c2s[k] = s;
    }

    const int n = blockIdx.x * 64 + lane;        // vector id
    const int b = n >> 14;                       // LHW = 2^14
    const int p = n & (LHWc - 1);

    const float* xin = in + (size_t)b * (Cc * LHWc) + p;

    float x[Dc];
#pragma unroll
    for (int d = 0; d < Dc; ++d) x[d] = xin[(size_t)d * LHWc];

    float x2 = 0.f;
#pragma unroll
    for (int d = 0; d < Dc; ++d) x2 = __builtin_fmaf(x[d], x[d], x2);

    unsigned long long best = ~0ull;
    const float4* cb4 = (const float4*)codebook;

#pragma unroll 1
    for (int ch = 0; ch < NCHUNK; ++ch) {
        __syncthreads();                         // prev chunk fully consumed
        // stage 2048 float4 (32 KB) with 256 threads: coalesced 16B loads,
        // contiguous conflict-free b128 LDS writes
#pragma unroll
        for (int i = 0; i < 8; ++i)
            cchunk[i * 256 + tid] = cb4[ch * 2048 + i * 256 + tid];
        __syncthreads();

        const int kbase = ch * CHUNK + wave * CPW;
#pragma unroll 2
        for (int j = 0; j < CPW; ++j) {
            const int k = kbase + j;             // wave-uniform
            const float4* row = &cchunk[(wave * CPW + j) * 16];
            // exact sequential fma chain d = 0..63 (bit-identical to r2-r5);
            // ds_read_b128 at wave-uniform address = LDS broadcast, no conflict
            float acc = 0.f;
#pragma unroll
            for (int q = 0; q < 16; ++q) {
                float4 f = row[q];
                acc = __builtin_fmaf(x[q * 4 + 0], f.x, acc);
                acc = __builtin_fmaf(x[q * 4 + 1], f.y, acc);
                acc = __builtin_fmaf(x[q * 4 + 2], f.z, acc);
                acc = __builtin_fmaf(x[q * 4 + 3], f.w, acc);
            }
            // reference rounding: d2 = fl(fl(x2 - fl(2*dot)) + c2)
            float t  = __builtin_fmaf(-2.0f, acc, x2);
            float d2 = t + c2s[k];
            // d2 > 0 -> float bits order as uint; k in low bits -> u64 min
            // keeps the lowest k on ties, independent of scan order
            unsigned long long pk =
                ((unsigned long long)__float_as_uint(d2) << 32) | (unsigned)k;
            best = pk < best ? pk : best;
        }
    }

    red[wave * 64 + lane] = best;
    __syncthreads();

    if (wave == 0) {
        unsigned long long bb = red[lane];
#pragma unroll
        for (int w = 1; w < WAVES; ++w) {
            unsigned long long o = red[w * 64 + lane];
            bb = o < bb ? o : bb;
        }
        const int k = (int)(bb & 0xffffffffu);

        out[OFF_IDX + n] = (float)k;

        const float* ck = codebook + (size_t)k * Dc;
        float* qout = out + (size_t)b * (Cc * LHWc) + p;
        float lsum = 0.f;
#pragma unroll
        for (int c = 0; c < Dc; ++c) {
            float q = ck[c];
            qout[(size_t)c * LHWc] = q;          // coalesced across lanes per c
            float e = q - x[c];
            lsum = __builtin_fmaf(e, e, lsum);
        }
#pragma unroll
        for (int off = 32; off > 0; off >>= 1)
            lsum += __shfl_down(lsum, off, 64);
        if (lane == 0)
            atomicAdd(&out[OFF_LOSS], lsum * (1.25f / (float)QSIZE));
    }
}

extern "C" void kernel_launch(void* const* d_in, const int* in_sizes, int n_in,
                              void* d_out, int out_size, void* d_ws, size_t ws_size,
                              hipStream_t stream) {
    const float* in = (const float*)d_in[0];   // [4,64,16,32,32] f32
    const float* cb = (const float*)d_in[1];   // [1024,64] f32
    float* out = (float*)d_out;
    (void)d_ws; (void)ws_size;

    vq_zero<<<dim3(1), dim3(1), 0, stream>>>(out);
    vq_main<<<dim3(Nc / 64), dim3(WAVES * 64), 0, stream>>>(in, cb, out);
}